// Round 3
// baseline (2101.395 us; speedup 1.0000x reference)
//
#include <hip/hip_runtime.h>
#include <math.h>

typedef unsigned short u16;
typedef __attribute__((ext_vector_type(8))) short bf16x8;
typedef __attribute__((ext_vector_type(4))) float f32x4;

#define NH 12
#define SCALE 0.1767766952966369f

// split 8 floats -> bf16 hi/lo fragments (RNE), x ~= hi + lo, ~2^-17 rel err
__device__ __forceinline__ void split8(const float* v, bf16x8& hi, bf16x8& lo) {
    #pragma unroll
    for (int j = 0; j < 8; ++j) {
        union { float f; unsigned u; } a; a.f = v[j];
        unsigned r = a.u + 0x7FFFu + ((a.u >> 16) & 1u);
        u16 h = (u16)(r >> 16);
        union { unsigned u; float f; } b; b.u = (unsigned)h << 16;
        union { float f; unsigned u; } c; c.f = v[j] - b.f;
        unsigned r2 = c.u + 0x7FFFu + ((c.u >> 16) & 1u);
        hi[j] = (short)h; lo[j] = (short)(r2 >> 16);
    }
}

// ---------------------------------------------------------------------------
// Kernel A: per-window fused QKV (split-bf16 MFMA, head-PAIR passes) + attn.
// x kept in REGISTERS (per-lane k-slices); qkv_w staged once per pair.
// grid=1024 windows, block=256 (4 waves = 4 row-tiles of 16).
// ---------------------------------------------------------------------------
__global__ __launch_bounds__(256, 2) void wmsa_attn_kernel(
    const float* __restrict__ x, const float* __restrict__ qkv_w,
    const float* __restrict__ qkv_b, const float* __restrict__ rel_table,
    float* __restrict__ out)
{
    __shared__ __align__(16) u16 bt_hi[192][40];   // 15360 B
    __shared__ __align__(16) u16 bt_lo[192][40];   // 15360 B
    __shared__ __align__(16) float qs[52][36];     //  7488 B
    __shared__ __align__(16) float kss[52][36];    //  7488 B
    __shared__ __align__(16) float vst[32][56];    //  7168 B
    __shared__ __align__(16) float at[52][56];     // 11648 B  => 64512 B

    const int wi = blockIdx.x, bi = wi >> 6, win = wi & 63;
    const int wy = win >> 3, wx = win & 7;
    const int tid = threadIdx.x, lane = tid & 63, wm = tid >> 6;
    const int ln = lane & 15, kg = lane >> 4, koff = kg * 8;
    const int arow = wm * 16 + ln;

    // ---- A: x row -> register frags (hi/lo), per-lane k-slice per ksi ----
    bf16x8 axh[12], axl[12];
    {
        const bool live = (arow < 49);
        const float* xr = x;
        if (live) {
            int Y = wy * 7 + arow / 7, X = wx * 7 + arow % 7;
            xr = x + (size_t)((bi * 56 + Y) * 56 + X) * 384;
        }
        #pragma unroll
        for (int s = 0; s < 12; ++s) {
            float v[8];
            if (live) {
                float4 a = *reinterpret_cast<const float4*>(xr + s * 32 + koff);
                float4 b = *reinterpret_cast<const float4*>(xr + s * 32 + koff + 4);
                v[0]=a.x; v[1]=a.y; v[2]=a.z; v[3]=a.w;
                v[4]=b.x; v[5]=b.y; v[6]=b.z; v[7]=b.w;
            } else {
                #pragma unroll
                for (int j = 0; j < 8; ++j) v[j] = 0.f;
            }
            split8(v, axh[s], axl[s]);
        }
    }

    // B staging task decode: 768 tasks = 192 cols x 4 k-blocks, 3/thread
    float rr[3][8];
    int tc[3], tk8[3];
    #pragma unroll
    for (int t = 0; t < 3; ++t) { int idx = tid + t * 256; tc[t] = idx % 192; tk8[t] = idx / 192; }

    auto loadB = [&](int p, int ksi) {
        #pragma unroll
        for (int t = 0; t < 3; ++t) {
            int c = tc[t], m = c >> 6, d = c & 63;
            const float* wp = qkv_w + (size_t)(ksi * 32 + tk8[t] * 8) * 1152
                              + m * 384 + p * 64 + d;
            #pragma unroll
            for (int j = 0; j < 8; ++j) rr[t][j] = wp[(size_t)j * 1152];
        }
    };

    loadB(0, 0);

    for (int p = 0; p < 6; ++p) {              // head pairs (h = 2p, 2p+1)
        f32x4 acc[12];
        #pragma unroll
        for (int f = 0; f < 12; ++f) { acc[f][0]=0.f; acc[f][1]=0.f; acc[f][2]=0.f; acc[f][3]=0.f; }

        #pragma unroll
        for (int ksi = 0; ksi < 12; ++ksi) {
            __syncthreads();                   // prior bt readers done
            #pragma unroll
            for (int t = 0; t < 3; ++t) {      // write-late: regs -> LDS (b128)
                bf16x8 h, l; split8(rr[t], h, l);
                *reinterpret_cast<bf16x8*>(&bt_hi[tc[t]][tk8[t] * 8]) = h;
                *reinterpret_cast<bf16x8*>(&bt_lo[tc[t]][tk8[t] * 8]) = l;
            }
            __syncthreads();
            if (ksi < 11) loadB(p, ksi + 1);   // issue-early next chunk
            else if (p < 5) loadB(p + 1, 0);
            #pragma unroll
            for (int f = 0; f < 12; ++f) {
                bf16x8 bh = *reinterpret_cast<const bf16x8*>(&bt_hi[f * 16 + ln][koff]);
                bf16x8 bl = *reinterpret_cast<const bf16x8*>(&bt_lo[f * 16 + ln][koff]);
                acc[f] = __builtin_amdgcn_mfma_f32_16x16x32_bf16(axh[ksi], bh, acc[f], 0, 0, 0);
                acc[f] = __builtin_amdgcn_mfma_f32_16x16x32_bf16(axh[ksi], bl, acc[f], 0, 0, 0);
                acc[f] = __builtin_amdgcn_mfma_f32_16x16x32_bf16(axl[ksi], bh, acc[f], 0, 0, 0);
            }
        }

        // ---- attention for the two heads of this pair ----
        for (int hh = 0; hh < 2; ++hh) {
            const int h = p * 2 + hh;
            // scatter q (scaled+bias) / k / v^T from acc to LDS
            #pragma unroll
            for (int m = 0; m < 3; ++m) {
                #pragma unroll
                for (int g = 0; g < 2; ++g) {
                    const int f = m * 4 + hh * 2 + g;
                    const int d = g * 16 + ln;
                    const float bias = qkv_b[m * 384 + h * 32 + d];
                    #pragma unroll
                    for (int r = 0; r < 4; ++r) {
                        const int row = wm * 16 + kg * 4 + r;
                        if (row < 52) {
                            float val = acc[f][r] + bias;
                            if (m == 0)      qs[row][d]  = val * SCALE;
                            else if (m == 1) kss[row][d] = val;
                            else             vst[d][row] = val;
                        }
                    }
                }
            }
            __syncthreads();

            // S = q k^T  (169 threads, 4x4 tiles)
            if (tid < 169) {
                const int n0 = (tid / 13) * 4, m0 = (tid % 13) * 4;
                float s[4][4] = {};
                #pragma unroll
                for (int k = 0; k < 32; k += 4) {
                    float4 qa[4], kb[4];
                    #pragma unroll
                    for (int i = 0; i < 4; ++i) qa[i] = *reinterpret_cast<const float4*>(&qs[n0 + i][k]);
                    #pragma unroll
                    for (int j = 0; j < 4; ++j) kb[j] = *reinterpret_cast<const float4*>(&kss[m0 + j][k]);
                    #pragma unroll
                    for (int i = 0; i < 4; ++i)
                        #pragma unroll
                        for (int j = 0; j < 4; ++j)
                            s[i][j] += qa[i].x * kb[j].x + qa[i].y * kb[j].y +
                                       qa[i].z * kb[j].z + qa[i].w * kb[j].w;
                }
                #pragma unroll
                for (int i = 0; i < 4; ++i)
                    #pragma unroll
                    for (int j = 0; j < 4; ++j)
                        at[n0 + i][m0 + j] = s[i][j];
            }
            __syncthreads();

            // softmax per row (wave per row) + bias AFTER softmax
            for (int r = wm; r < 49; r += 4) {
                float v = (lane < 49) ? at[r][lane] : -3.4e38f;
                float mx = v;
                #pragma unroll
                for (int off = 32; off; off >>= 1) mx = fmaxf(mx, __shfl_xor(mx, off));
                float e = (lane < 49) ? __expf(v - mx) : 0.f;
                float ssum = e;
                #pragma unroll
                for (int off = 32; off; off >>= 1) ssum += __shfl_xor(ssum, off);
                if (lane < 52) {
                    float res = 0.f;
                    if (lane < 49) {
                        int py = r / 7, px = r % 7, qy = lane / 7, qx = lane % 7;
                        int bidx = (py - qy + 6) * 13 + (px - qx + 6);
                        res = e / ssum + rel_table[bidx * NH + h];
                    }
                    at[r][lane] = res;
                }
            }
            __syncthreads();

            // out_h = attn @ v  (208 threads, 4x2 tiles) + store
            if (tid < 208) {
                const int n0 = (tid / 16) * 4, d0 = (tid % 16) * 2;
                float o[4][2] = {};
                #pragma unroll
                for (int m2 = 0; m2 < 52; m2 += 4) {
                    float4 pa[4], vb[2];
                    #pragma unroll
                    for (int i = 0; i < 4; ++i) pa[i] = *reinterpret_cast<const float4*>(&at[n0 + i][m2]);
                    #pragma unroll
                    for (int j = 0; j < 2; ++j) vb[j] = *reinterpret_cast<const float4*>(&vst[d0 + j][m2]);
                    #pragma unroll
                    for (int i = 0; i < 4; ++i)
                        #pragma unroll
                        for (int j = 0; j < 2; ++j)
                            o[i][j] += pa[i].x * vb[j].x + pa[i].y * vb[j].y +
                                       pa[i].z * vb[j].z + pa[i].w * vb[j].w;
                }
                #pragma unroll
                for (int i = 0; i < 4; ++i) {
                    int n = n0 + i;
                    if (n < 49) {
                        int Y = wy * 7 + n / 7, X = wx * 7 + n % 7;
                        size_t base = (size_t)((bi * 56 + Y) * 56 + X) * 384 + h * 32 + d0;
                        *reinterpret_cast<float2*>(out + base) = make_float2(o[i][0], o[i][1]);
                    }
                }
            }
            __syncthreads();
        }
    }
}

// ---------------------------------------------------------------------------
// Kernel B: output projection via split-bf16 MFMA, IN PLACE on d_out.
// Block owns 64 token rows x ALL 384 cols (no cross-block row sharing).
// grid=784, block=512 (8 waves: 4 row-tiles x 2 col-halves).
// ---------------------------------------------------------------------------
__global__ __launch_bounds__(512, 2) void wmsa_proj_kernel(
    const float* __restrict__ proj_w, const float* __restrict__ proj_b,
    float* __restrict__ out)
{
    __shared__ __align__(16) u16 bt_hi[384][40];   // 30720 B
    __shared__ __align__(16) u16 bt_lo[384][40];   // 30720 B

    const int tid = threadIdx.x, lane = tid & 63, wv = tid >> 6;
    const int wm = wv >> 1, wn = wv & 1;
    const int ln = lane & 15, kg = lane >> 4, koff = kg * 8;
    const size_t tok0 = (size_t)blockIdx.x * 64;
    const int arow = wm * 16 + ln;

    // A: attn-out rows -> register frags (hi/lo). All loads precede stores.
    bf16x8 axh[12], axl[12];
    {
        const float* xr = out + (tok0 + arow) * 384;
        #pragma unroll
        for (int s = 0; s < 12; ++s) {
            float v[8];
            float4 a = *reinterpret_cast<const float4*>(xr + s * 32 + koff);
            float4 b = *reinterpret_cast<const float4*>(xr + s * 32 + koff + 4);
            v[0]=a.x; v[1]=a.y; v[2]=a.z; v[3]=a.w;
            v[4]=b.x; v[5]=b.y; v[6]=b.z; v[7]=b.w;
            split8(v, axh[s], axl[s]);
        }
    }

    float rr[3][8];
    int tc[3], tk8[3];
    #pragma unroll
    for (int t = 0; t < 3; ++t) { int idx = tid + t * 512; tc[t] = idx % 384; tk8[t] = idx / 384; }

    auto loadB = [&](int ksi) {
        #pragma unroll
        for (int t = 0; t < 3; ++t) {
            const float* wp = proj_w + (size_t)(ksi * 32 + tk8[t] * 8) * 384 + tc[t];
            #pragma unroll
            for (int j = 0; j < 8; ++j) rr[t][j] = wp[(size_t)j * 384];
        }
    };

    loadB(0);
    f32x4 acc[12];
    #pragma unroll
    for (int f = 0; f < 12; ++f) { acc[f][0]=0.f; acc[f][1]=0.f; acc[f][2]=0.f; acc[f][3]=0.f; }

    #pragma unroll
    for (int ksi = 0; ksi < 12; ++ksi) {
        __syncthreads();
        #pragma unroll
        for (int t = 0; t < 3; ++t) {
            bf16x8 h, l; split8(rr[t], h, l);
            *reinterpret_cast<bf16x8*>(&bt_hi[tc[t]][tk8[t] * 8]) = h;
            *reinterpret_cast<bf16x8*>(&bt_lo[tc[t]][tk8[t] * 8]) = l;
        }
        __syncthreads();
        if (ksi < 11) loadB(ksi + 1);
        #pragma unroll
        for (int f = 0; f < 12; ++f) {
            int n = wn * 192 + f * 16 + ln;
            bf16x8 bh = *reinterpret_cast<const bf16x8*>(&bt_hi[n][koff]);
            bf16x8 bl = *reinterpret_cast<const bf16x8*>(&bt_lo[n][koff]);
            acc[f] = __builtin_amdgcn_mfma_f32_16x16x32_bf16(axh[ksi], bh, acc[f], 0, 0, 0);
            acc[f] = __builtin_amdgcn_mfma_f32_16x16x32_bf16(axh[ksi], bl, acc[f], 0, 0, 0);
            acc[f] = __builtin_amdgcn_mfma_f32_16x16x32_bf16(axl[ksi], bh, acc[f], 0, 0, 0);
        }
    }
    __syncthreads();   // all A-loads (every wave) retired long before stores

    #pragma unroll
    for (int f = 0; f < 12; ++f) {
        int n = wn * 192 + f * 16 + ln;
        float pb = proj_b[n];
        #pragma unroll
        for (int r = 0; r < 4; ++r) {
            int row = wm * 16 + kg * 4 + r;
            out[(tok0 + row) * 384 + n] = acc[f][r] + pb;
        }
    }
}

extern "C" void kernel_launch(void* const* d_in, const int* in_sizes, int n_in,
                              void* d_out, int out_size, void* d_ws, size_t ws_size,
                              hipStream_t stream) {
    const float* x         = (const float*)d_in[0];
    const float* qkv_w     = (const float*)d_in[1];
    const float* qkv_b     = (const float*)d_in[2];
    const float* proj_w    = (const float*)d_in[3];
    const float* proj_b    = (const float*)d_in[4];
    const float* rel_table = (const float*)d_in[5];
    float* out = (float*)d_out;

    hipLaunchKernelGGL(wmsa_attn_kernel, dim3(1024), dim3(256), 0, stream,
                       x, qkv_w, qkv_b, rel_table, out);
    hipLaunchKernelGGL(wmsa_proj_kernel, dim3(784), dim3(512), 0, stream,
                       proj_w, proj_b, out);
}

// Round 4
// 1734.110 us; speedup vs baseline: 1.2118x; 1.2118x over previous
//
#include <hip/hip_runtime.h>

typedef unsigned short u16;
typedef __attribute__((ext_vector_type(8))) short bf16x8;
typedef __attribute__((ext_vector_type(4))) float f32x4;

#define NH 12
#define SCALE 0.1767766952966369f

// split 8 floats -> bf16 hi/lo (RNE), x ~= hi+lo, ~2^-17 rel err
__device__ __forceinline__ void split8(const float* v, bf16x8& hi, bf16x8& lo) {
    #pragma unroll
    for (int j = 0; j < 8; ++j) {
        union { float f; unsigned u; } a; a.f = v[j];
        unsigned r = a.u + 0x7FFFu + ((a.u >> 16) & 1u);
        u16 h = (u16)(r >> 16);
        union { unsigned u; float f; } b; b.u = (unsigned)h << 16;
        union { float f; unsigned u; } c; c.f = v[j] - b.f;
        unsigned r2 = c.u + 0x7FFFu + ((c.u >> 16) & 1u);
        hi[j] = (short)h; lo[j] = (short)(r2 >> 16);
    }
}

// byte offset of 16B granule g (0..7) in swizzled row (pitch 128 B = 64 u16)
__device__ __forceinline__ int swz(int row, int g) {
    return row * 128 + (((g ^ (row & 7)) & 7) << 4);
}

// ---------------------------------------------------------------------------
// Kernel A: per-window QKV (split-bf16 MFMA, head-pair passes) + fp32 attn.
// grid=1024 windows, block=512 (8 waves = 4 row-tiles x 2 col-halves).
// LDS: weight tile [192][64] hi/lo (swizzled) OVERLAID with attn buffers.
// ---------------------------------------------------------------------------
__global__ __launch_bounds__(512) void wmsa_attn_kernel(
    const float* __restrict__ x, const float* __restrict__ qkv_w,
    const float* __restrict__ qkv_b, const float* __restrict__ rel_table,
    float* __restrict__ out)
{
    __shared__ __align__(16) char smem[55936];
    u16* bt_hi = (u16*)smem;                    // [192][64] swizzled, 24576 B
    u16* bt_lo = (u16*)(smem + 24576);          // 24576 B
    // overlay (weight tile dead during attention phases):
    float* qs  = (float*)smem;                  // [2][52][36] 14976 B
    float* kss = (float*)(smem + 14976);        // [2][52][36] 14976 B
    float* vst = (float*)(smem + 29952);        // [2][32][56] 14336 B
    float* at  = (float*)(smem + 44288);        // [52][56]    11648 B

    const int wi = blockIdx.x, bi = wi >> 6, win = wi & 63;
    const int wy = win >> 3, wx = win & 7;
    const int tid = threadIdx.x, lane = tid & 63;
    const int wv = tid >> 6, wm = wv >> 1, wn = wv & 1;
    const int ln = lane & 15, kq = lane >> 4;
    const int arow = wm * 16 + ln;

    // A-operand row pointer (rows >=49 duplicate row 0: finite, masked later)
    int Y = wy * 7, X = wx * 7;
    if (arow < 49) { Y += arow / 7; X += arow % 7; }
    const float* xr = x + (size_t)((bi * 56 + Y) * 56 + X) * 384;

    // staging tasks: 3/thread; idx -> col c (consecutive per wave), kg fixed
    int tcol[3], tkg[3];
    #pragma unroll
    for (int t = 0; t < 3; ++t) { int idx = tid + t * 512; tcol[t] = idx % 192; tkg[t] = idx / 192; }
    float rr[3][8];

    auto loadB = [&](int p, int ck) {
        #pragma unroll
        for (int t = 0; t < 3; ++t) {
            int c = tcol[t];
            int n = (c >> 6) * 384 + p * 64 + (c & 63);
            const float* wp = qkv_w + (size_t)(ck * 64 + tkg[t] * 8) * 1152 + n;
            #pragma unroll
            for (int j = 0; j < 8; ++j) rr[t][j] = wp[(size_t)j * 1152];
        }
    };

    loadB(0, 0);

    #pragma unroll 1
    for (int p = 0; p < 6; ++p) {               // head pair p -> heads 2p,2p+1
        f32x4 acc[6];
        #pragma unroll
        for (int f = 0; f < 6; ++f) { acc[f][0]=0.f; acc[f][1]=0.f; acc[f][2]=0.f; acc[f][3]=0.f; }

        #pragma unroll 1
        for (int ck = 0; ck < 6; ++ck) {        // K chunks of 64
            __syncthreads();                    // prev readers of bt/overlay done
            #pragma unroll
            for (int t = 0; t < 3; ++t) {
                bf16x8 h, l; split8(rr[t], h, l);
                *(bf16x8*)((char*)bt_hi + swz(tcol[t], tkg[t])) = h;
                *(bf16x8*)((char*)bt_lo + swz(tcol[t], tkg[t])) = l;
            }
            __syncthreads();
            if (ck < 5) loadB(p, ck + 1);       // issue-early next chunk
            else if (p < 5) loadB(p + 1, 0);
            #pragma unroll
            for (int ks = 0; ks < 2; ++ks) {    // two 32-k MFMA steps
                float av[8];
                const float* xp = xr + ck * 64 + ks * 32 + kq * 8;
                float4 a0 = *(const float4*)xp;
                float4 a1 = *(const float4*)(xp + 4);
                av[0]=a0.x; av[1]=a0.y; av[2]=a0.z; av[3]=a0.w;
                av[4]=a1.x; av[5]=a1.y; av[6]=a1.z; av[7]=a1.w;
                bf16x8 ah, al; split8(av, ah, al);
                #pragma unroll
                for (int f = 0; f < 6; ++f) {
                    int n = wn * 96 + f * 16 + ln;
                    int off = swz(n, ks * 4 + kq);
                    bf16x8 bh = *(const bf16x8*)((char*)bt_hi + off);
                    bf16x8 bl = *(const bf16x8*)((char*)bt_lo + off);
                    acc[f] = __builtin_amdgcn_mfma_f32_16x16x32_bf16(ah, bh, acc[f], 0, 0, 0);
                    acc[f] = __builtin_amdgcn_mfma_f32_16x16x32_bf16(ah, bl, acc[f], 0, 0, 0);
                    acc[f] = __builtin_amdgcn_mfma_f32_16x16x32_bf16(al, bh, acc[f], 0, 0, 0);
                }
            }
        }
        __syncthreads();                        // bt reads done before overlay

        // scatter acc -> q (scaled+bias) / k / v^T for BOTH heads of pair
        #pragma unroll
        for (int f = 0; f < 6; ++f) {
            int c = wn * 96 + f * 16 + ln;
            int m = c >> 6, d = c & 63, hh = d >> 5, dd = d & 31;
            float bias = qkv_b[m * 384 + p * 64 + d];
            #pragma unroll
            for (int r = 0; r < 4; ++r) {
                int row = wm * 16 + kq * 4 + r;
                if (row < 52) {
                    float val = acc[f][r] + bias;
                    if (m == 0)      qs [(hh * 52 + row) * 36 + dd] = val * SCALE;
                    else if (m == 1) kss[(hh * 52 + row) * 36 + dd] = val;
                    else             vst[(hh * 32 + dd) * 56 + row] = val;
                }
            }
        }
        __syncthreads();

        for (int hh = 0; hh < 2; ++hh) {
            const int h = p * 2 + hh;
            const float* qsh = qs  + hh * 52 * 36;
            const float* ksh = kss + hh * 52 * 36;
            const float* vsh = vst + hh * 32 * 56;

            // S = q k^T  (169 threads, 4x4 tiles)
            if (tid < 169) {
                const int n0 = (tid / 13) * 4, m0 = (tid % 13) * 4;
                float s[4][4] = {};
                #pragma unroll
                for (int k = 0; k < 32; k += 4) {
                    float4 qa[4], kb[4];
                    #pragma unroll
                    for (int i = 0; i < 4; ++i) qa[i] = *(const float4*)&qsh[(n0 + i) * 36 + k];
                    #pragma unroll
                    for (int j = 0; j < 4; ++j) kb[j] = *(const float4*)&ksh[(m0 + j) * 36 + k];
                    #pragma unroll
                    for (int i = 0; i < 4; ++i)
                        #pragma unroll
                        for (int j = 0; j < 4; ++j)
                            s[i][j] += qa[i].x * kb[j].x + qa[i].y * kb[j].y +
                                       qa[i].z * kb[j].z + qa[i].w * kb[j].w;
                }
                #pragma unroll
                for (int i = 0; i < 4; ++i)
                    #pragma unroll
                    for (int j = 0; j < 4; ++j)
                        at[(n0 + i) * 56 + m0 + j] = s[i][j];
            }
            __syncthreads();

            // softmax per row (wave per row) + bias AFTER softmax
            for (int r = wv; r < 49; r += 8) {
                float v = (lane < 49) ? at[r * 56 + lane] : -3.4e38f;
                float mx = v;
                #pragma unroll
                for (int off = 32; off; off >>= 1) mx = fmaxf(mx, __shfl_xor(mx, off));
                float e = (lane < 49) ? __expf(v - mx) : 0.f;
                float ssum = e;
                #pragma unroll
                for (int off = 32; off; off >>= 1) ssum += __shfl_xor(ssum, off);
                if (lane < 52) {
                    float res = 0.f;
                    if (lane < 49) {
                        int py = r / 7, px = r % 7, qy = lane / 7, qx = lane % 7;
                        int bidx = (py - qy + 6) * 13 + (px - qx + 6);
                        res = e / ssum + rel_table[bidx * NH + h];
                    }
                    at[r * 56 + lane] = res;   // zero pad cols 49..51
                }
            }
            __syncthreads();

            // out_h = attn @ v  (208 threads, 4x2 tiles) + store
            if (tid < 208) {
                const int n0 = (tid / 16) * 4, d0 = (tid % 16) * 2;
                float o[4][2] = {};
                #pragma unroll
                for (int m2 = 0; m2 < 52; m2 += 4) {
                    float4 pa[4], vb[2];
                    #pragma unroll
                    for (int i = 0; i < 4; ++i) pa[i] = *(const float4*)&at[(n0 + i) * 56 + m2];
                    #pragma unroll
                    for (int j = 0; j < 2; ++j) vb[j] = *(const float4*)&vsh[(d0 + j) * 56 + m2];
                    #pragma unroll
                    for (int i = 0; i < 4; ++i)
                        #pragma unroll
                        for (int j = 0; j < 2; ++j)
                            o[i][j] += pa[i].x * vb[j].x + pa[i].y * vb[j].y +
                                       pa[i].z * vb[j].z + pa[i].w * vb[j].w;
                }
                #pragma unroll
                for (int i = 0; i < 4; ++i) {
                    int n = n0 + i;
                    if (n < 49) {
                        int Yo = wy * 7 + n / 7, Xo = wx * 7 + n % 7;
                        size_t base = (size_t)((bi * 56 + Yo) * 56 + Xo) * 384 + h * 32 + d0;
                        *(float2*)(out + base) = make_float2(o[i][0], o[i][1]);
                    }
                }
            }
            __syncthreads();
        }
    }
}

// ---------------------------------------------------------------------------
// Kernel B: output projection, split-bf16 MFMA, IN PLACE on d_out.
// Single pass N=384 (acc holds full row-stripe) so no read-after-write hazard;
// barrier before epilogue guarantees all A-loads retired before stores.
// grid=784 (64 rows), block=512.
// ---------------------------------------------------------------------------
__global__ __launch_bounds__(512) void wmsa_proj_kernel(
    const float* __restrict__ proj_w, const float* __restrict__ proj_b,
    float* __restrict__ out)
{
    __shared__ __align__(16) char smem[98304];
    u16* bt_hi = (u16*)smem;                    // [384][64] swizzled
    u16* bt_lo = (u16*)(smem + 49152);

    const int tid = threadIdx.x, lane = tid & 63;
    const int wv = tid >> 6, wm = wv >> 1, wn = wv & 1;
    const int ln = lane & 15, kq = lane >> 4;
    const size_t tok0 = (size_t)blockIdx.x * 64;
    const float* xr = out + (tok0 + wm * 16 + ln) * 384;

    int tcol[6], tkg[6];
    #pragma unroll
    for (int t = 0; t < 6; ++t) { int idx = tid + t * 512; tcol[t] = idx % 384; tkg[t] = idx / 384; }
    float rr[6][8];
    auto loadB = [&](int ck) {
        #pragma unroll
        for (int t = 0; t < 6; ++t) {
            const float* wp = proj_w + (size_t)(ck * 64 + tkg[t] * 8) * 384 + tcol[t];
            #pragma unroll
            for (int j = 0; j < 8; ++j) rr[t][j] = wp[(size_t)j * 384];
        }
    };
    loadB(0);

    f32x4 acc[12];
    #pragma unroll
    for (int f = 0; f < 12; ++f) { acc[f][0]=0.f; acc[f][1]=0.f; acc[f][2]=0.f; acc[f][3]=0.f; }

    #pragma unroll 1
    for (int ck = 0; ck < 6; ++ck) {
        __syncthreads();
        #pragma unroll
        for (int t = 0; t < 6; ++t) {
            bf16x8 h, l; split8(rr[t], h, l);
            *(bf16x8*)((char*)bt_hi + swz(tcol[t], tkg[t])) = h;
            *(bf16x8*)((char*)bt_lo + swz(tcol[t], tkg[t])) = l;
        }
        __syncthreads();
        if (ck < 5) loadB(ck + 1);
        #pragma unroll
        for (int ks = 0; ks < 2; ++ks) {
            float av[8];
            const float* xp = xr + ck * 64 + ks * 32 + kq * 8;
            float4 a0 = *(const float4*)xp;
            float4 a1 = *(const float4*)(xp + 4);
            av[0]=a0.x; av[1]=a0.y; av[2]=a0.z; av[3]=a0.w;
            av[4]=a1.x; av[5]=a1.y; av[6]=a1.z; av[7]=a1.w;
            bf16x8 ah, al; split8(av, ah, al);
            #pragma unroll
            for (int f = 0; f < 12; ++f) {
                int n = wn * 192 + f * 16 + ln;
                int off = swz(n, ks * 4 + kq);
                bf16x8 bh = *(const bf16x8*)((char*)bt_hi + off);
                bf16x8 bl = *(const bf16x8*)((char*)bt_lo + off);
                acc[f] = __builtin_amdgcn_mfma_f32_16x16x32_bf16(ah, bh, acc[f], 0, 0, 0);
                acc[f] = __builtin_amdgcn_mfma_f32_16x16x32_bf16(ah, bl, acc[f], 0, 0, 0);
                acc[f] = __builtin_amdgcn_mfma_f32_16x16x32_bf16(al, bh, acc[f], 0, 0, 0);
            }
        }
    }
    __syncthreads();   // all waves' in-place A-loads retired before stores

    #pragma unroll
    for (int f = 0; f < 12; ++f) {
        int n = wn * 192 + f * 16 + ln;
        float pb = proj_b[n];
        #pragma unroll
        for (int r = 0; r < 4; ++r)
            out[(tok0 + wm * 16 + kq * 4 + r) * 384 + n] = acc[f][r] + pb;
    }
}

extern "C" void kernel_launch(void* const* d_in, const int* in_sizes, int n_in,
                              void* d_out, int out_size, void* d_ws, size_t ws_size,
                              hipStream_t stream) {
    const float* x         = (const float*)d_in[0];
    const float* qkv_w     = (const float*)d_in[1];
    const float* qkv_b     = (const float*)d_in[2];
    const float* proj_w    = (const float*)d_in[3];
    const float* proj_b    = (const float*)d_in[4];
    const float* rel_table = (const float*)d_in[5];
    float* out = (float*)d_out;

    hipLaunchKernelGGL(wmsa_attn_kernel, dim3(1024), dim3(512), 0, stream,
                       x, qkv_w, qkv_b, rel_table, out);
    hipLaunchKernelGGL(wmsa_proj_kernel, dim3(784), dim3(512), 0, stream,
                       proj_w, proj_b, out);
}

// Round 7
// 690.597 us; speedup vs baseline: 3.0429x; 2.5110x over previous
//
#include <hip/hip_runtime.h>

typedef unsigned short u16;
typedef __attribute__((ext_vector_type(8))) short bf16x8;
typedef __attribute__((ext_vector_type(4))) float f32x4;

#define NH 12
#define SCALE 0.1767766952966369f

// split 8 floats -> bf16 hi/lo (RNE), x ~= hi+lo, ~2^-17 rel err
__device__ __forceinline__ void split8(const float* v, bf16x8& hi, bf16x8& lo) {
    #pragma unroll
    for (int j = 0; j < 8; ++j) {
        union { float f; unsigned u; } a; a.f = v[j];
        unsigned r = a.u + 0x7FFFu + ((a.u >> 16) & 1u);
        u16 h = (u16)(r >> 16);
        union { unsigned u; float f; } b; b.u = (unsigned)h << 16;
        union { float f; unsigned u; } c; c.f = v[j] - b.f;
        unsigned r2 = c.u + 0x7FFFu + ((c.u >> 16) & 1u);
        hi[j] = (short)h; lo[j] = (short)(r2 >> 16);
    }
}

// byte offset of 16B granule g (0..7) in swizzled row (pitch 128 B = 64 u16)
__device__ __forceinline__ int swz(int row, int g) {
    return row * 128 + (((g ^ (row & 7)) & 7) << 4);
}

// ===========================================================================
// PATH A, kernel 1: QKV GEMM  [50176,384]x[384,1152] via split-bf16 MFMA.
// grid = 784 token-tiles x 3 slabs (slab: 0=Q,1=K,2=V); block=512.
// Writes ws per (global win, head): Q[64][32] | K[64][32] | V[64][32] fp32.
// ===========================================================================
__global__ __launch_bounds__(512) void qkv_gemm_kernel(
    const float* __restrict__ x, const float* __restrict__ qkv_w,
    const float* __restrict__ qkv_b, float* __restrict__ ws)
{
    __shared__ __align__(16) char smem[98304];
    u16* bt_hi = (u16*)smem;                    // [384][64] swizzled
    u16* bt_lo = (u16*)(smem + 49152);

    const int bid = blockIdx.x;
    const int s = bid % 3;                      // uniform per block
    const size_t tok0 = (size_t)(bid / 3) * 64;
    const int tid = threadIdx.x, lane = tid & 63;
    const int wv = tid >> 6, wm = wv >> 1, wn = wv & 1;
    const int ln = lane & 15, kq = lane >> 4;
    const float* xr = x + (tok0 + wm * 16 + ln) * 384;

    int tcol[6], tkg[6];
    #pragma unroll
    for (int t = 0; t < 6; ++t) { int idx = tid + t * 512; tcol[t] = idx % 384; tkg[t] = idx / 384; }
    float rr[6][8];
    auto loadB = [&](int ck) {
        #pragma unroll
        for (int t = 0; t < 6; ++t) {
            const float* wp = qkv_w + (size_t)(ck * 64 + tkg[t] * 8) * 1152 + s * 384 + tcol[t];
            #pragma unroll
            for (int j = 0; j < 8; ++j) rr[t][j] = wp[(size_t)j * 1152];
        }
    };
    loadB(0);

    f32x4 acc[12];
    #pragma unroll
    for (int f = 0; f < 12; ++f) { acc[f][0]=0.f; acc[f][1]=0.f; acc[f][2]=0.f; acc[f][3]=0.f; }

    #pragma unroll 1
    for (int ck = 0; ck < 6; ++ck) {
        __syncthreads();
        #pragma unroll
        for (int t = 0; t < 6; ++t) {
            bf16x8 h, l; split8(rr[t], h, l);
            *(bf16x8*)((char*)bt_hi + swz(tcol[t], tkg[t])) = h;
            *(bf16x8*)((char*)bt_lo + swz(tcol[t], tkg[t])) = l;
        }
        __syncthreads();
        if (ck < 5) loadB(ck + 1);
        #pragma unroll
        for (int ks = 0; ks < 2; ++ks) {
            float av[8];
            const float* xp = xr + ck * 64 + ks * 32 + kq * 8;
            float4 a0 = *(const float4*)xp;
            float4 a1 = *(const float4*)(xp + 4);
            av[0]=a0.x; av[1]=a0.y; av[2]=a0.z; av[3]=a0.w;
            av[4]=a1.x; av[5]=a1.y; av[6]=a1.z; av[7]=a1.w;
            bf16x8 ah, al; split8(av, ah, al);
            #pragma unroll
            for (int f = 0; f < 12; ++f) {
                int n = wn * 192 + f * 16 + ln;
                int off = swz(n, ks * 4 + kq);
                bf16x8 bh = *(const bf16x8*)((char*)bt_hi + off);
                bf16x8 bl = *(const bf16x8*)((char*)bt_lo + off);
                acc[f] = __builtin_amdgcn_mfma_f32_16x16x32_bf16(ah, bh, acc[f], 0, 0, 0);
                acc[f] = __builtin_amdgcn_mfma_f32_16x16x32_bf16(ah, bl, acc[f], 0, 0, 0);
                acc[f] = __builtin_amdgcn_mfma_f32_16x16x32_bf16(al, bh, acc[f], 0, 0, 0);
            }
        }
    }

    // epilogue: decode 4 tokens -> (global window, in-window row); scatter
    int wwin[4], wrow[4];
    #pragma unroll
    for (int r = 0; r < 4; ++r) {
        int t = (int)tok0 + wm * 16 + kq * 4 + r;
        int b_i = t / 3136, rem = t % 3136, y = rem / 56, xx = rem % 56;
        wwin[r] = b_i * 64 + (y / 7) * 8 + (xx / 7);
        wrow[r] = (y % 7) * 7 + (xx % 7);
    }
    #pragma unroll
    for (int f = 0; f < 12; ++f) {
        int n_local = wn * 192 + f * 16 + ln;
        int hh = n_local >> 5, dd = n_local & 31;
        float bias = qkv_b[s * 384 + n_local];
        #pragma unroll
        for (int r = 0; r < 4; ++r) {
            float val = acc[f][r] + bias;
            size_t base = (size_t)(wwin[r] * 12 + hh) * 6144;
            if (s == 0)      ws[base + wrow[r] * 32 + dd] = val * SCALE;
            else if (s == 1) ws[base + 2048 + wrow[r] * 32 + dd] = val;
            else             ws[base + 4096 + wrow[r] * 32 + dd] = val;
        }
    }
}

// ===========================================================================
// PATH A, kernel 2: attention core. One block per GLOBAL window (256 thr).
// S^T = K·Q^T via split-bf16 MFMA; cross-wave softmax via LDS;
// bias AFTER softmax; PV via split-bf16 MFMA.
// ===========================================================================
__global__ __launch_bounds__(256) void attn_core_kernel(
    const float* __restrict__ ws, const float* __restrict__ rel_table,
    float* __restrict__ out)
{
    __shared__ __align__(16) float pt[64][68];     // P' [query n][key m]
    __shared__ __align__(16) float rel_all[2048];  // rel_table copy
    __shared__ float pmax[4][64];
    __shared__ float psum[4][64];

    const int wi = blockIdx.x, bi = wi >> 6, win = wi & 63;
    const int wy = win >> 3, wx = win & 7;
    const int tid = threadIdx.x, lane = tid & 63, wv = tid >> 6;
    const int ln = lane & 15, kq = lane >> 4;

    for (int i = tid; i < 2028; i += 256) rel_all[i] = rel_table[i];

    // lane's key rows (also PV-out query rows): m = wv*16 + kq*4 + r
    int m7[4], mr[4], outY[4], outX[4];
    bool mok[4];
    #pragma unroll
    for (int r = 0; r < 4; ++r) {
        int m = wv * 16 + kq * 4 + r;
        mok[r] = (m < 49);
        int a = mok[r] ? m : 0;
        m7[r] = a / 7; mr[r] = a % 7;
        outY[r] = wy * 7 + m7[r]; outX[r] = wx * 7 + mr[r];
    }
    // lane's query cols: n = nt*16 + ln
    int n7[4], nr[4];
    #pragma unroll
    for (int nt = 0; nt < 4; ++nt) {
        int n = nt * 16 + ln, a = (n < 49) ? n : 0;
        n7[nt] = a / 7; nr[nt] = a % 7;
    }
    const int mK = wv * 16 + ln;        // K-row for this lane's S A-frag

    for (int h = 0; h < NH; ++h) {
        const float* qb = ws + (size_t)(wi * 12 + h) * 6144;   // GLOBAL window
        const float* kb = qb + 2048;
        const float* vb = qb + 4096;

        // ---- S^T tiles (key tile = wv, query tiles nt = 0..3) ----
        bf16x8 kh, kl;
        {
            float v[8];
            #pragma unroll
            for (int j = 0; j < 8; ++j) v[j] = 0.f;
            if (mK < 49) {
                float4 a0 = *(const float4*)(kb + mK * 32 + kq * 8);
                float4 a1 = *(const float4*)(kb + mK * 32 + kq * 8 + 4);
                v[0]=a0.x; v[1]=a0.y; v[2]=a0.z; v[3]=a0.w;
                v[4]=a1.x; v[5]=a1.y; v[6]=a1.z; v[7]=a1.w;
            }
            split8(v, kh, kl);
        }
        f32x4 accs[4];
        #pragma unroll
        for (int nt = 0; nt < 4; ++nt) {
            int n = nt * 16 + ln;
            float v[8];
            #pragma unroll
            for (int j = 0; j < 8; ++j) v[j] = 0.f;
            if (n < 49) {
                float4 a0 = *(const float4*)(qb + n * 32 + kq * 8);
                float4 a1 = *(const float4*)(qb + n * 32 + kq * 8 + 4);
                v[0]=a0.x; v[1]=a0.y; v[2]=a0.z; v[3]=a0.w;
                v[4]=a1.x; v[5]=a1.y; v[6]=a1.z; v[7]=a1.w;
            }
            bf16x8 qh, ql; split8(v, qh, ql);
            f32x4 z; z[0]=0.f; z[1]=0.f; z[2]=0.f; z[3]=0.f;
            z = __builtin_amdgcn_mfma_f32_16x16x32_bf16(kh, qh, z, 0, 0, 0);
            z = __builtin_amdgcn_mfma_f32_16x16x32_bf16(kh, ql, z, 0, 0, 0);
            z = __builtin_amdgcn_mfma_f32_16x16x32_bf16(kl, qh, z, 0, 0, 0);
            accs[nt] = z;
        }

        // ---- softmax over keys m (cross-wave via LDS) ----
        float e[4][4], gmax[4], ginv[4];
        #pragma unroll
        for (int nt = 0; nt < 4; ++nt) {
            float lm = -3.4e38f;
            #pragma unroll
            for (int r = 0; r < 4; ++r) if (mok[r]) lm = fmaxf(lm, accs[nt][r]);
            lm = fmaxf(lm, __shfl_xor(lm, 16));
            lm = fmaxf(lm, __shfl_xor(lm, 32));
            if (kq == 0) pmax[wv][nt * 16 + ln] = lm;
        }
        __syncthreads();
        #pragma unroll
        for (int nt = 0; nt < 4; ++nt) {
            int n = nt * 16 + ln;
            gmax[nt] = fmaxf(fmaxf(pmax[0][n], pmax[1][n]), fmaxf(pmax[2][n], pmax[3][n]));
            float ls = 0.f;
            #pragma unroll
            for (int r = 0; r < 4; ++r) {
                e[nt][r] = mok[r] ? __expf(accs[nt][r] - gmax[nt]) : 0.f;
                ls += e[nt][r];
            }
            ls += __shfl_xor(ls, 16);
            ls += __shfl_xor(ls, 32);
            if (kq == 0) psum[wv][nt * 16 + ln] = ls;
        }
        __syncthreads();
        #pragma unroll
        for (int nt = 0; nt < 4; ++nt) {
            int n = nt * 16 + ln;
            ginv[nt] = 1.f / (psum[0][n] + psum[1][n] + psum[2][n] + psum[3][n]);
            #pragma unroll
            for (int r = 0; r < 4; ++r) {
                float val = 0.f;
                if (mok[r]) {
                    int bidx = (n7[nt] - m7[r] + 6) * 13 + (nr[nt] - mr[r] + 6);
                    val = e[nt][r] * ginv[nt] + rel_all[bidx * NH + h];
                }
                pt[n][wv * 16 + kq * 4 + r] = val;
            }
        }
        __syncthreads();

        // ---- PV: out rows n = wv*16.., cols d (2 tiles of 16) ----
        bf16x8 pah[2], pal[2];
        #pragma unroll
        for (int mc = 0; mc < 2; ++mc) {
            const float* pp = &pt[wv * 16 + ln][mc * 32 + kq * 8];
            float v[8];
            float4 a0 = *(const float4*)pp;
            float4 a1 = *(const float4*)(pp + 4);
            v[0]=a0.x; v[1]=a0.y; v[2]=a0.z; v[3]=a0.w;
            v[4]=a1.x; v[5]=a1.y; v[6]=a1.z; v[7]=a1.w;
            split8(v, pah[mc], pal[mc]);
        }
        f32x4 acco[2];
        #pragma unroll
        for (int dt = 0; dt < 2; ++dt) { acco[dt][0]=0.f; acco[dt][1]=0.f; acco[dt][2]=0.f; acco[dt][3]=0.f; }
        #pragma unroll
        for (int dt = 0; dt < 2; ++dt) {
            #pragma unroll
            for (int mc = 0; mc < 2; ++mc) {
                float v[8];
                #pragma unroll
                for (int j = 0; j < 8; ++j) {
                    int m = mc * 32 + kq * 8 + j;
                    v[j] = (m < 49) ? vb[m * 32 + dt * 16 + ln] : 0.f;
                }
                bf16x8 vh, vl; split8(v, vh, vl);
                acco[dt] = __builtin_amdgcn_mfma_f32_16x16x32_bf16(pah[mc], vh, acco[dt], 0, 0, 0);
                acco[dt] = __builtin_amdgcn_mfma_f32_16x16x32_bf16(pah[mc], vl, acco[dt], 0, 0, 0);
                acco[dt] = __builtin_amdgcn_mfma_f32_16x16x32_bf16(pal[mc], vh, acco[dt], 0, 0, 0);
            }
        }
        #pragma unroll
        for (int r = 0; r < 4; ++r) {
            if (mok[r]) {
                size_t base = (size_t)((bi * 56 + outY[r]) * 56 + outX[r]) * 384 + h * 32;
                out[base + ln]      = acco[0][r];
                out[base + 16 + ln] = acco[1][r];
            }
        }
        __syncthreads();
    }
}

// ===========================================================================
// PATH B fallback (small ws): R4 fused per-window kernel (proven correct).
// ===========================================================================
__global__ __launch_bounds__(512) void wmsa_attn_kernel(
    const float* __restrict__ x, const float* __restrict__ qkv_w,
    const float* __restrict__ qkv_b, const float* __restrict__ rel_table,
    float* __restrict__ out)
{
    __shared__ __align__(16) char smem[55936];
    u16* bt_hi = (u16*)smem;
    u16* bt_lo = (u16*)(smem + 24576);
    float* qs  = (float*)smem;
    float* kss = (float*)(smem + 14976);
    float* vst = (float*)(smem + 29952);
    float* at  = (float*)(smem + 44288);

    const int wi = blockIdx.x, bi = wi >> 6, win = wi & 63;
    const int wy = win >> 3, wx = win & 7;
    const int tid = threadIdx.x, lane = tid & 63;
    const int wv = tid >> 6, wm = wv >> 1, wn = wv & 1;
    const int ln = lane & 15, kq = lane >> 4;
    const int arow = wm * 16 + ln;

    int Y = wy * 7, X = wx * 7;
    if (arow < 49) { Y += arow / 7; X += arow % 7; }
    const float* xr = x + (size_t)((bi * 56 + Y) * 56 + X) * 384;

    int tcol[3], tkg[3];
    #pragma unroll
    for (int t = 0; t < 3; ++t) { int idx = tid + t * 512; tcol[t] = idx % 192; tkg[t] = idx / 192; }
    float rr[3][8];
    auto loadB = [&](int p, int ck) {
        #pragma unroll
        for (int t = 0; t < 3; ++t) {
            int c = tcol[t];
            int n = (c >> 6) * 384 + p * 64 + (c & 63);
            const float* wp = qkv_w + (size_t)(ck * 64 + tkg[t] * 8) * 1152 + n;
            #pragma unroll
            for (int j = 0; j < 8; ++j) rr[t][j] = wp[(size_t)j * 1152];
        }
    };
    loadB(0, 0);

    #pragma unroll 1
    for (int p = 0; p < 6; ++p) {
        f32x4 acc[6];
        #pragma unroll
        for (int f = 0; f < 6; ++f) { acc[f][0]=0.f; acc[f][1]=0.f; acc[f][2]=0.f; acc[f][3]=0.f; }
        #pragma unroll 1
        for (int ck = 0; ck < 6; ++ck) {
            __syncthreads();
            #pragma unroll
            for (int t = 0; t < 3; ++t) {
                bf16x8 h, l; split8(rr[t], h, l);
                *(bf16x8*)((char*)bt_hi + swz(tcol[t], tkg[t])) = h;
                *(bf16x8*)((char*)bt_lo + swz(tcol[t], tkg[t])) = l;
            }
            __syncthreads();
            if (ck < 5) loadB(p, ck + 1);
            else if (p < 5) loadB(p + 1, 0);
            #pragma unroll
            for (int ks = 0; ks < 2; ++ks) {
                float av[8];
                const float* xp = xr + ck * 64 + ks * 32 + kq * 8;
                float4 a0 = *(const float4*)xp;
                float4 a1 = *(const float4*)(xp + 4);
                av[0]=a0.x; av[1]=a0.y; av[2]=a0.z; av[3]=a0.w;
                av[4]=a1.x; av[5]=a1.y; av[6]=a1.z; av[7]=a1.w;
                bf16x8 ah, al; split8(av, ah, al);
                #pragma unroll
                for (int f = 0; f < 6; ++f) {
                    int n = wn * 96 + f * 16 + ln;
                    int off = swz(n, ks * 4 + kq);
                    bf16x8 bh = *(const bf16x8*)((char*)bt_hi + off);
                    bf16x8 bl = *(const bf16x8*)((char*)bt_lo + off);
                    acc[f] = __builtin_amdgcn_mfma_f32_16x16x32_bf16(ah, bh, acc[f], 0, 0, 0);
                    acc[f] = __builtin_amdgcn_mfma_f32_16x16x32_bf16(ah, bl, acc[f], 0, 0, 0);
                    acc[f] = __builtin_amdgcn_mfma_f32_16x16x32_bf16(al, bh, acc[f], 0, 0, 0);
                }
            }
        }
        __syncthreads();
        #pragma unroll
        for (int f = 0; f < 6; ++f) {
            int c = wn * 96 + f * 16 + ln;
            int m = c >> 6, d = c & 63, hh = d >> 5, dd = d & 31;
            float bias = qkv_b[m * 384 + p * 64 + d];
            #pragma unroll
            for (int r = 0; r < 4; ++r) {
                int row = wm * 16 + kq * 4 + r;
                if (row < 52) {
                    float val = acc[f][r] + bias;
                    if (m == 0)      qs [(hh * 52 + row) * 36 + dd] = val * SCALE;
                    else if (m == 1) kss[(hh * 52 + row) * 36 + dd] = val;
                    else             vst[(hh * 32 + dd) * 56 + row] = val;
                }
            }
        }
        __syncthreads();
        for (int hh = 0; hh < 2; ++hh) {
            const int h = p * 2 + hh;
            const float* qsh = qs  + hh * 52 * 36;
            const float* ksh = kss + hh * 52 * 36;
            const float* vsh = vst + hh * 32 * 56;
            if (tid < 169) {
                const int n0 = (tid / 13) * 4, m0 = (tid % 13) * 4;
                float s[4][4] = {};
                #pragma unroll
                for (int k = 0; k < 32; k += 4) {
                    float4 qa[4], kb[4];
                    #pragma unroll
                    for (int i = 0; i < 4; ++i) qa[i] = *(const float4*)&qsh[(n0 + i) * 36 + k];
                    #pragma unroll
                    for (int j = 0; j < 4; ++j) kb[j] = *(const float4*)&ksh[(m0 + j) * 36 + k];
                    #pragma unroll
                    for (int i = 0; i < 4; ++i)
                        #pragma unroll
                        for (int j = 0; j < 4; ++j)
                            s[i][j] += qa[i].x * kb[j].x + qa[i].y * kb[j].y +
                                       qa[i].z * kb[j].z + qa[i].w * kb[j].w;
                }
                #pragma unroll
                for (int i = 0; i < 4; ++i)
                    #pragma unroll
                    for (int j = 0; j < 4; ++j)
                        at[(n0 + i) * 56 + m0 + j] = s[i][j];
            }
            __syncthreads();
            for (int r = wv; r < 49; r += 8) {
                float v = (lane < 49) ? at[r * 56 + lane] : -3.4e38f;
                float mx = v;
                #pragma unroll
                for (int off = 32; off; off >>= 1) mx = fmaxf(mx, __shfl_xor(mx, off));
                float ex = (lane < 49) ? __expf(v - mx) : 0.f;
                float ssum = ex;
                #pragma unroll
                for (int off = 32; off; off >>= 1) ssum += __shfl_xor(ssum, off);
                if (lane < 52) {
                    float res = 0.f;
                    if (lane < 49) {
                        int py = r / 7, px = r % 7, qy = lane / 7, qx = lane % 7;
                        int bidx = (py - qy + 6) * 13 + (px - qx + 6);
                        res = ex / ssum + rel_table[bidx * NH + h];
                    }
                    at[r * 56 + lane] = res;
                }
            }
            __syncthreads();
            if (tid < 208) {
                const int n0 = (tid / 16) * 4, d0 = (tid % 16) * 2;
                float o[4][2] = {};
                #pragma unroll
                for (int m2 = 0; m2 < 52; m2 += 4) {
                    float4 pa[4], vb2[2];
                    #pragma unroll
                    for (int i = 0; i < 4; ++i) pa[i] = *(const float4*)&at[(n0 + i) * 56 + m2];
                    #pragma unroll
                    for (int j = 0; j < 2; ++j) vb2[j] = *(const float4*)&vsh[(d0 + j) * 56 + m2];
                    #pragma unroll
                    for (int i = 0; i < 4; ++i)
                        #pragma unroll
                        for (int j = 0; j < 2; ++j)
                            o[i][j] += pa[i].x * vb2[j].x + pa[i].y * vb2[j].y +
                                       pa[i].z * vb2[j].z + pa[i].w * vb2[j].w;
                }
                #pragma unroll
                for (int i = 0; i < 4; ++i) {
                    int n = n0 + i;
                    if (n < 49) {
                        int Yo = wy * 7 + n / 7, Xo = wx * 7 + n % 7;
                        size_t base = (size_t)((bi * 56 + Yo) * 56 + Xo) * 384 + h * 32 + d0;
                        *(float2*)(out + base) = make_float2(o[i][0], o[i][1]);
                    }
                }
            }
            __syncthreads();
        }
    }
}

// ===========================================================================
// Kernel 3 (both paths): output projection, split-bf16 MFMA, IN PLACE.
// ===========================================================================
__global__ __launch_bounds__(512) void wmsa_proj_kernel(
    const float* __restrict__ proj_w, const float* __restrict__ proj_b,
    float* __restrict__ out)
{
    __shared__ __align__(16) char smem[98304];
    u16* bt_hi = (u16*)smem;
    u16* bt_lo = (u16*)(smem + 49152);

    const int tid = threadIdx.x, lane = tid & 63;
    const int wv = tid >> 6, wm = wv >> 1, wn = wv & 1;
    const int ln = lane & 15, kq = lane >> 4;
    const size_t tok0 = (size_t)blockIdx.x * 64;
    const float* xr = out + (tok0 + wm * 16 + ln) * 384;

    int tcol[6], tkg[6];
    #pragma unroll
    for (int t = 0; t < 6; ++t) { int idx = tid + t * 512; tcol[t] = idx % 384; tkg[t] = idx / 384; }
    float rr[6][8];
    auto loadB = [&](int ck) {
        #pragma unroll
        for (int t = 0; t < 6; ++t) {
            const float* wp = proj_w + (size_t)(ck * 64 + tkg[t] * 8) * 384 + tcol[t];
            #pragma unroll
            for (int j = 0; j < 8; ++j) rr[t][j] = wp[(size_t)j * 384];
        }
    };
    loadB(0);

    f32x4 acc[12];
    #pragma unroll
    for (int f = 0; f < 12; ++f) { acc[f][0]=0.f; acc[f][1]=0.f; acc[f][2]=0.f; acc[f][3]=0.f; }

    #pragma unroll 1
    for (int ck = 0; ck < 6; ++ck) {
        __syncthreads();
        #pragma unroll
        for (int t = 0; t < 6; ++t) {
            bf16x8 h, l; split8(rr[t], h, l);
            *(bf16x8*)((char*)bt_hi + swz(tcol[t], tkg[t])) = h;
            *(bf16x8*)((char*)bt_lo + swz(tcol[t], tkg[t])) = l;
        }
        __syncthreads();
        if (ck < 5) loadB(ck + 1);
        #pragma unroll
        for (int ks = 0; ks < 2; ++ks) {
            float av[8];
            const float* xp = xr + ck * 64 + ks * 32 + kq * 8;
            float4 a0 = *(const float4*)xp;
            float4 a1 = *(const float4*)(xp + 4);
            av[0]=a0.x; av[1]=a0.y; av[2]=a0.z; av[3]=a0.w;
            av[4]=a1.x; av[5]=a1.y; av[6]=a1.z; av[7]=a1.w;
            bf16x8 ah, al; split8(av, ah, al);
            #pragma unroll
            for (int f = 0; f < 12; ++f) {
                int n = wn * 192 + f * 16 + ln;
                int off = swz(n, ks * 4 + kq);
                bf16x8 bh = *(const bf16x8*)((char*)bt_hi + off);
                bf16x8 bl = *(const bf16x8*)((char*)bt_lo + off);
                acc[f] = __builtin_amdgcn_mfma_f32_16x16x32_bf16(ah, bh, acc[f], 0, 0, 0);
                acc[f] = __builtin_amdgcn_mfma_f32_16x16x32_bf16(ah, bl, acc[f], 0, 0, 0);
                acc[f] = __builtin_amdgcn_mfma_f32_16x16x32_bf16(al, bh, acc[f], 0, 0, 0);
            }
        }
    }
    __syncthreads();

    #pragma unroll
    for (int f = 0; f < 12; ++f) {
        int n = wn * 192 + f * 16 + ln;
        float pb = proj_b[n];
        #pragma unroll
        for (int r = 0; r < 4; ++r)
            out[(tok0 + wm * 16 + kq * 4 + r) * 384 + n] = acc[f][r] + pb;
    }
}

extern "C" void kernel_launch(void* const* d_in, const int* in_sizes, int n_in,
                              void* d_out, int out_size, void* d_ws, size_t ws_size,
                              hipStream_t stream) {
    const float* x         = (const float*)d_in[0];
    const float* qkv_w     = (const float*)d_in[1];
    const float* qkv_b     = (const float*)d_in[2];
    const float* proj_w    = (const float*)d_in[3];
    const float* proj_b    = (const float*)d_in[4];
    const float* rel_table = (const float*)d_in[5];
    float* out = (float*)d_out;
    float* wsf = (float*)d_ws;

    const size_t WS_NEED = (size_t)12288 * 6144 * 4;   // 301,989,888 B

    if (ws_size >= WS_NEED) {
        hipLaunchKernelGGL(qkv_gemm_kernel, dim3(2352), dim3(512), 0, stream,
                           x, qkv_w, qkv_b, wsf);
        hipLaunchKernelGGL(attn_core_kernel, dim3(1024), dim3(256), 0, stream,
                           wsf, rel_table, out);
    } else {
        hipLaunchKernelGGL(wmsa_attn_kernel, dim3(1024), dim3(512), 0, stream,
                           x, qkv_w, qkv_b, rel_table, out);
    }
    hipLaunchKernelGGL(wmsa_proj_kernel, dim3(784), dim3(512), 0, stream,
                       proj_w, proj_b, out);
}

// Round 8
// 617.560 us; speedup vs baseline: 3.4027x; 1.1183x over previous
//
#include <hip/hip_runtime.h>

typedef unsigned short u16;
typedef __attribute__((ext_vector_type(8))) short bf16x8;
typedef __attribute__((ext_vector_type(4))) float f32x4;

#define NH 12
#define SCALE 0.1767766952966369f

// ---- ws layout (bytes) ----
// R0: per (global win, head) unit, stride 20992:
//   Qhi[49][32]u16 @0      Qlo @3136   Khi @6272   Klo @9408
//   Vthi[32][64]u16 @12544 Vtlo @16640            (end 20736)
#define UNIT 20992
#define WS_R0    ((size_t)0)
#define WS_QKVB  ((size_t)12288 * UNIT)                 // 257,949,696
#define WS_PROJB (WS_QKVB + (size_t)3 * 12 * 49152)     // +1,769,472
#define WS_NEED  (WS_PROJB + (size_t)12 * 49152)        // +589,824 = 260,308,992

// split fp32 -> bf16 hi/lo (RNE), x ~= hi+lo
__device__ __forceinline__ void split2(float x, u16& h, u16& l) {
    union { float f; unsigned u; } a; a.f = x;
    unsigned r = a.u + 0x7FFFu + ((a.u >> 16) & 1u);
    h = (u16)(r >> 16);
    union { unsigned u; float f; } b; b.u = (unsigned)h << 16;
    union { float f; unsigned u; } c; c.f = x - b.f;
    unsigned r2 = c.u + 0x7FFFu + ((c.u >> 16) & 1u);
    l = (u16)(r2 >> 16);
}
__device__ __forceinline__ void split8(const float* v, bf16x8& hi, bf16x8& lo) {
    #pragma unroll
    for (int j = 0; j < 8; ++j) {
        u16 h, l; split2(v[j], h, l);
        hi[j] = (short)h; lo[j] = (short)l;
    }
}

// old-path swizzle (granule 0..7, pitch 128 B)
__device__ __forceinline__ int swz(int row, int g) {
    return row * 128 + (((g ^ (row & 7)) & 7) << 4);
}

// ===========================================================================
// prep: pre-split qkv_w / proj_w into swizzled LDS-image chunks in ws.
// Image per (slab,ck): [384 rows][32 k] u16 hi (24576 B) then lo (24576 B).
// LDS byte o for (row, kl): o = row*64 + ((kl>>3)^(row&3))*16 + (kl&7)*2.
// grid = 1536 blocks x 384 thr (b<1152: qkv; else proj).
// ===========================================================================
__global__ __launch_bounds__(384) void prep_kernel(
    const float* __restrict__ qkv_w, const float* __restrict__ proj_w,
    char* __restrict__ ws)
{
    const int b = blockIdx.x, row = threadIdx.x;
    float w; size_t base;
    int kl;
    if (b < 1152) {
        int s = b / 384, r = b % 384, ck = r / 32; kl = r % 32;
        w = qkv_w[(size_t)(ck * 32 + kl) * 1152 + s * 384 + row];
        base = WS_QKVB + (size_t)(s * 12 + ck) * 49152;
    } else {
        int b1 = b - 1152, ck = b1 / 32; kl = b1 % 32;
        w = proj_w[(size_t)(ck * 32 + kl) * 384 + row];
        base = WS_PROJB + (size_t)ck * 49152;
    }
    u16 h, l; split2(w, h, l);
    int o = row * 64 + ((((kl >> 3) ^ row) & 3) << 4) + (kl & 7) * 2;
    *(u16*)(ws + base + o)         = h;
    *(u16*)(ws + base + 24576 + o) = l;
}

// ===========================================================================
// QKV GEMM: [50176,384]x[384,384/slab] via split-bf16 MFMA, BK=32.
// grid = 784 token-tiles x 3 slabs; block=512; LDS 48 KB -> 3 blocks/CU.
// Epilogue: Q/K stored pre-split hi/lo bf16; V stored TRANSPOSED hi/lo.
// ===========================================================================
__global__ __launch_bounds__(512) void qkv_gemm_kernel(
    const float* __restrict__ x, const char* __restrict__ wsB,
    const float* __restrict__ qkv_b, char* __restrict__ ws)
{
    __shared__ __align__(16) char bt[49152];   // hi [0,24576), lo [24576,49152)

    const int bid = blockIdx.x;
    const int s = bid % 3;
    const size_t tok0 = (size_t)(bid / 3) * 64;
    const int tid = threadIdx.x, lane = tid & 63;
    const int wv = tid >> 6, wm = wv >> 1, wn = wv & 1;
    const int ln = lane & 15, kq = lane >> 4;
    const float* xr = x + (tok0 + wm * 16 + ln) * 384;
    const char* wB = wsB + WS_QKVB + (size_t)s * 12 * 49152;

    bf16x8 st[6];
    #pragma unroll
    for (int i = 0; i < 6; ++i)
        st[i] = *(const bf16x8*)(wB + (size_t)tid * 16 + i * 8192);

    f32x4 acc[12];
    #pragma unroll
    for (int f = 0; f < 12; ++f) { acc[f][0]=0.f; acc[f][1]=0.f; acc[f][2]=0.f; acc[f][3]=0.f; }

    #pragma unroll 1
    for (int ck = 0; ck < 12; ++ck) {
        __syncthreads();                 // prior MFMA reads of bt done
        #pragma unroll
        for (int i = 0; i < 6; ++i)
            *(bf16x8*)(bt + tid * 16 + i * 8192) = st[i];
        __syncthreads();
        if (ck < 11) {                   // issue-early next chunk
            const char* nb = wB + (size_t)(ck + 1) * 49152;
            #pragma unroll
            for (int i = 0; i < 6; ++i)
                st[i] = *(const bf16x8*)(nb + (size_t)tid * 16 + i * 8192);
        }
        // A: 8 floats of this k-chunk, split on the fly
        float av[8];
        {
            const float* xp = xr + ck * 32 + kq * 8;
            float4 a0 = *(const float4*)xp;
            float4 a1 = *(const float4*)(xp + 4);
            av[0]=a0.x; av[1]=a0.y; av[2]=a0.z; av[3]=a0.w;
            av[4]=a1.x; av[5]=a1.y; av[6]=a1.z; av[7]=a1.w;
        }
        bf16x8 ah, al; split8(av, ah, al);
        #pragma unroll
        for (int f = 0; f < 12; ++f) {
            int n = wn * 192 + f * 16 + ln;
            int off = n * 64 + (((kq ^ n) & 3) << 4);
            bf16x8 bh = *(const bf16x8*)(bt + off);
            bf16x8 bl = *(const bf16x8*)(bt + 24576 + off);
            acc[f] = __builtin_amdgcn_mfma_f32_16x16x32_bf16(ah, bh, acc[f], 0, 0, 0);
            acc[f] = __builtin_amdgcn_mfma_f32_16x16x32_bf16(ah, bl, acc[f], 0, 0, 0);
            acc[f] = __builtin_amdgcn_mfma_f32_16x16x32_bf16(al, bh, acc[f], 0, 0, 0);
        }
    }

    // epilogue: decode tokens -> (global window, in-window row); store split
    int wwin[4], wrow[4];
    #pragma unroll
    for (int r = 0; r < 4; ++r) {
        int t = (int)tok0 + wm * 16 + kq * 4 + r;
        int b_i = t / 3136, rem = t % 3136, y = rem / 56, xx = rem % 56;
        wwin[r] = b_i * 64 + (y / 7) * 8 + (xx / 7);
        wrow[r] = (y % 7) * 7 + (xx % 7);
    }
    #pragma unroll
    for (int f = 0; f < 12; ++f) {
        int n_local = wn * 192 + f * 16 + ln;
        int hh = n_local >> 5, dd = n_local & 31;
        float bias = qkv_b[s * 384 + n_local];
        #pragma unroll
        for (int r = 0; r < 4; ++r) {
            float val = acc[f][r] + bias;
            if (s == 0) val *= SCALE;
            u16 h, l; split2(val, h, l);
            u16* u = (u16*)(ws + WS_R0 + (size_t)(wwin[r] * 12 + hh) * UNIT);
            if (s == 0)      { u[wrow[r] * 32 + dd] = h;        u[1568 + wrow[r] * 32 + dd] = l; }
            else if (s == 1) { u[3136 + wrow[r] * 32 + dd] = h; u[4704 + wrow[r] * 32 + dd] = l; }
            else             { u[6272 + dd * 64 + wrow[r]] = h; u[8320 + dd * 64 + wrow[r]] = l; }
        }
    }
}

// ===========================================================================
// attention core: one block per GLOBAL window (256 thr = 4 waves).
// Q/K/Vt pre-split in ws. S^T = K*Q^T; cross-wave softmax; bias AFTER
// softmax; PV with Vt bf16x8 loads.
// ===========================================================================
__global__ __launch_bounds__(256) void attn_core_kernel(
    const char* __restrict__ ws, const float* __restrict__ rel_table,
    float* __restrict__ out)
{
    __shared__ __align__(16) float pt[64][68];
    __shared__ __align__(16) float rel_all[2048];
    __shared__ float pmax[4][64];
    __shared__ float psum[4][64];

    const int wi = blockIdx.x, bi = wi >> 6, win = wi & 63;
    const int wy = win >> 3, wx = win & 7;
    const int tid = threadIdx.x, lane = tid & 63, wv = tid >> 6;
    const int ln = lane & 15, kq = lane >> 4;

    for (int i = tid; i < 2028; i += 256) rel_all[i] = rel_table[i];

    int m7[4], mr[4], outY[4], outX[4];
    bool mok[4];
    #pragma unroll
    for (int r = 0; r < 4; ++r) {
        int m = wv * 16 + kq * 4 + r;
        mok[r] = (m < 49);
        int a = mok[r] ? m : 0;
        m7[r] = a / 7; mr[r] = a % 7;
        outY[r] = wy * 7 + m7[r]; outX[r] = wx * 7 + mr[r];
    }
    int n7[4], nr[4];
    #pragma unroll
    for (int nt = 0; nt < 4; ++nt) {
        int n = nt * 16 + ln, a = (n < 49) ? n : 0;
        n7[nt] = a / 7; nr[nt] = a % 7;
    }
    const int mK = wv * 16 + ln;
    bf16x8 zz; 
    #pragma unroll
    for (int j = 0; j < 8; ++j) zz[j] = 0;

    for (int h = 0; h < NH; ++h) {
        const u16* u = (const u16*)(ws + WS_R0 + (size_t)(wi * 12 + h) * UNIT);
        const u16* qhi = u,        * qlo = u + 1568;
        const u16* khi = u + 3136, * klo = u + 4704;
        const u16* vhi = u + 6272, * vlo = u + 8320;

        // ---- S^T tiles ----
        bf16x8 kh = zz, kl = zz;
        if (mK < 49) {
            kh = *(const bf16x8*)(khi + mK * 32 + kq * 8);
            kl = *(const bf16x8*)(klo + mK * 32 + kq * 8);
        }
        f32x4 accs[4];
        #pragma unroll
        for (int nt = 0; nt < 4; ++nt) {
            int n = nt * 16 + ln;
            bf16x8 qh = zz, ql = zz;
            if (n < 49) {
                qh = *(const bf16x8*)(qhi + n * 32 + kq * 8);
                ql = *(const bf16x8*)(qlo + n * 32 + kq * 8);
            }
            f32x4 z; z[0]=0.f; z[1]=0.f; z[2]=0.f; z[3]=0.f;
            z = __builtin_amdgcn_mfma_f32_16x16x32_bf16(kh, qh, z, 0, 0, 0);
            z = __builtin_amdgcn_mfma_f32_16x16x32_bf16(kh, ql, z, 0, 0, 0);
            z = __builtin_amdgcn_mfma_f32_16x16x32_bf16(kl, qh, z, 0, 0, 0);
            accs[nt] = z;
        }

        // ---- softmax over keys (cross-wave via LDS) ----
        float e[4][4], gmax[4], ginv[4];
        #pragma unroll
        for (int nt = 0; nt < 4; ++nt) {
            float lm = -3.4e38f;
            #pragma unroll
            for (int r = 0; r < 4; ++r) if (mok[r]) lm = fmaxf(lm, accs[nt][r]);
            lm = fmaxf(lm, __shfl_xor(lm, 16));
            lm = fmaxf(lm, __shfl_xor(lm, 32));
            if (kq == 0) pmax[wv][nt * 16 + ln] = lm;
        }
        __syncthreads();
        #pragma unroll
        for (int nt = 0; nt < 4; ++nt) {
            int n = nt * 16 + ln;
            gmax[nt] = fmaxf(fmaxf(pmax[0][n], pmax[1][n]), fmaxf(pmax[2][n], pmax[3][n]));
            float ls = 0.f;
            #pragma unroll
            for (int r = 0; r < 4; ++r) {
                e[nt][r] = mok[r] ? __expf(accs[nt][r] - gmax[nt]) : 0.f;
                ls += e[nt][r];
            }
            ls += __shfl_xor(ls, 16);
            ls += __shfl_xor(ls, 32);
            if (kq == 0) psum[wv][nt * 16 + ln] = ls;
        }
        __syncthreads();
        #pragma unroll
        for (int nt = 0; nt < 4; ++nt) {
            int n = nt * 16 + ln;
            ginv[nt] = 1.f / (psum[0][n] + psum[1][n] + psum[2][n] + psum[3][n]);
            #pragma unroll
            for (int r = 0; r < 4; ++r) {
                float val = 0.f;
                if (mok[r]) {
                    int bidx = (n7[nt] - m7[r] + 6) * 13 + (nr[nt] - mr[r] + 6);
                    val = e[nt][r] * ginv[nt] + rel_all[bidx * NH + h];
                }
                pt[n][wv * 16 + kq * 4 + r] = val;
            }
        }
        __syncthreads();

        // ---- PV ----
        bf16x8 pah[2], pal[2];
        #pragma unroll
        for (int mc = 0; mc < 2; ++mc) {
            const float* pp = &pt[wv * 16 + ln][mc * 32 + kq * 8];
            float v[8];
            float4 a0 = *(const float4*)pp;
            float4 a1 = *(const float4*)(pp + 4);
            v[0]=a0.x; v[1]=a0.y; v[2]=a0.z; v[3]=a0.w;
            v[4]=a1.x; v[5]=a1.y; v[6]=a1.z; v[7]=a1.w;
            split8(v, pah[mc], pal[mc]);
        }
        f32x4 acco[2];
        #pragma unroll
        for (int dt = 0; dt < 2; ++dt) { acco[dt][0]=0.f; acco[dt][1]=0.f; acco[dt][2]=0.f; acco[dt][3]=0.f; }
        #pragma unroll
        for (int dt = 0; dt < 2; ++dt) {
            int d = dt * 16 + ln;
            #pragma unroll
            for (int mc = 0; mc < 2; ++mc) {
                bf16x8 vh = *(const bf16x8*)(vhi + d * 64 + mc * 32 + kq * 8);
                bf16x8 vl = *(const bf16x8*)(vlo + d * 64 + mc * 32 + kq * 8);
                acco[dt] = __builtin_amdgcn_mfma_f32_16x16x32_bf16(pah[mc], vh, acco[dt], 0, 0, 0);
                acco[dt] = __builtin_amdgcn_mfma_f32_16x16x32_bf16(pah[mc], vl, acco[dt], 0, 0, 0);
                acco[dt] = __builtin_amdgcn_mfma_f32_16x16x32_bf16(pal[mc], vh, acco[dt], 0, 0, 0);
            }
        }
        #pragma unroll
        for (int r = 0; r < 4; ++r) {
            if (mok[r]) {
                size_t base = (size_t)((bi * 56 + outY[r]) * 56 + outX[r]) * 384 + h * 32;
                out[base + ln]      = acco[0][r];
                out[base + 16 + ln] = acco[1][r];
            }
        }
        __syncthreads();
    }
}

// ===========================================================================
// proj: [50176,384]x[384,384] via split-bf16 MFMA, BK=32, IN PLACE on out.
// grid=784, block=512, LDS 48 KB -> 3 blocks/CU.
// ===========================================================================
__global__ __launch_bounds__(512) void proj_kernel(
    const char* __restrict__ wsB, const float* __restrict__ proj_b,
    float* __restrict__ out)
{
    __shared__ __align__(16) char bt[49152];

    const int tid = threadIdx.x, lane = tid & 63;
    const int wv = tid >> 6, wm = wv >> 1, wn = wv & 1;
    const int ln = lane & 15, kq = lane >> 4;
    const size_t tok0 = (size_t)blockIdx.x * 64;
    const float* xr = out + (tok0 + wm * 16 + ln) * 384;
    const char* wB = wsB + WS_PROJB;

    bf16x8 st[6];
    #pragma unroll
    for (int i = 0; i < 6; ++i)
        st[i] = *(const bf16x8*)(wB + (size_t)tid * 16 + i * 8192);

    f32x4 acc[12];
    #pragma unroll
    for (int f = 0; f < 12; ++f) { acc[f][0]=0.f; acc[f][1]=0.f; acc[f][2]=0.f; acc[f][3]=0.f; }

    #pragma unroll 1
    for (int ck = 0; ck < 12; ++ck) {
        __syncthreads();
        #pragma unroll
        for (int i = 0; i < 6; ++i)
            *(bf16x8*)(bt + tid * 16 + i * 8192) = st[i];
        __syncthreads();
        if (ck < 11) {
            const char* nb = wB + (size_t)(ck + 1) * 49152;
            #pragma unroll
            for (int i = 0; i < 6; ++i)
                st[i] = *(const bf16x8*)(nb + (size_t)tid * 16 + i * 8192);
        }
        float av[8];
        {
            const float* xp = xr + ck * 32 + kq * 8;
            float4 a0 = *(const float4*)xp;
            float4 a1 = *(const float4*)(xp + 4);
            av[0]=a0.x; av[1]=a0.y; av[2]=a0.z; av[3]=a0.w;
            av[4]=a1.x; av[5]=a1.y; av[6]=a1.z; av[7]=a1.w;
        }
        bf16x8 ah, al; split8(av, ah, al);
        #pragma unroll
        for (int f = 0; f < 12; ++f) {
            int n = wn * 192 + f * 16 + ln;
            int off = n * 64 + (((kq ^ n) & 3) << 4);
            bf16x8 bh = *(const bf16x8*)(bt + off);
            bf16x8 bl = *(const bf16x8*)(bt + 24576 + off);
            acc[f] = __builtin_amdgcn_mfma_f32_16x16x32_bf16(ah, bh, acc[f], 0, 0, 0);
            acc[f] = __builtin_amdgcn_mfma_f32_16x16x32_bf16(ah, bl, acc[f], 0, 0, 0);
            acc[f] = __builtin_amdgcn_mfma_f32_16x16x32_bf16(al, bh, acc[f], 0, 0, 0);
        }
    }
    __syncthreads();   // all in-place A-loads retired before stores

    #pragma unroll
    for (int f = 0; f < 12; ++f) {
        int n = wn * 192 + f * 16 + ln;
        float pb = proj_b[n];
        #pragma unroll
        for (int r = 0; r < 4; ++r)
            out[(tok0 + wm * 16 + kq * 4 + r) * 384 + n] = acc[f][r] + pb;
    }
}

// ===========================================================================
// PATH B fallback (small ws): R4 fused per-window kernel + runtime-split proj.
// ===========================================================================
__global__ __launch_bounds__(512) void wmsa_attn_kernel(
    const float* __restrict__ x, const float* __restrict__ qkv_w,
    const float* __restrict__ qkv_b, const float* __restrict__ rel_table,
    float* __restrict__ out)
{
    __shared__ __align__(16) char smem[55936];
    u16* bt_hi = (u16*)smem;
    u16* bt_lo = (u16*)(smem + 24576);
    float* qs  = (float*)smem;
    float* kss = (float*)(smem + 14976);
    float* vst = (float*)(smem + 29952);
    float* at  = (float*)(smem + 44288);

    const int wi = blockIdx.x, bi = wi >> 6, win = wi & 63;
    const int wy = win >> 3, wx = win & 7;
    const int tid = threadIdx.x, lane = tid & 63;
    const int wv = tid >> 6, wm = wv >> 1, wn = wv & 1;
    const int ln = lane & 15, kq = lane >> 4;
    const int arow = wm * 16 + ln;

    int Y = wy * 7, X = wx * 7;
    if (arow < 49) { Y += arow / 7; X += arow % 7; }
    const float* xr = x + (size_t)((bi * 56 + Y) * 56 + X) * 384;

    int tcol[3], tkg[3];
    #pragma unroll
    for (int t = 0; t < 3; ++t) { int idx = tid + t * 512; tcol[t] = idx % 192; tkg[t] = idx / 192; }
    float rr[3][8];
    auto loadB = [&](int p, int ck) {
        #pragma unroll
        for (int t = 0; t < 3; ++t) {
            int c = tcol[t];
            int n = (c >> 6) * 384 + p * 64 + (c & 63);
            const float* wp = qkv_w + (size_t)(ck * 64 + tkg[t] * 8) * 1152 + n;
            #pragma unroll
            for (int j = 0; j < 8; ++j) rr[t][j] = wp[(size_t)j * 1152];
        }
    };
    loadB(0, 0);

    #pragma unroll 1
    for (int p = 0; p < 6; ++p) {
        f32x4 acc[6];
        #pragma unroll
        for (int f = 0; f < 6; ++f) { acc[f][0]=0.f; acc[f][1]=0.f; acc[f][2]=0.f; acc[f][3]=0.f; }
        #pragma unroll 1
        for (int ck = 0; ck < 6; ++ck) {
            __syncthreads();
            #pragma unroll
            for (int t = 0; t < 3; ++t) {
                bf16x8 h, l;
                split8(rr[t], h, l);
                *(bf16x8*)((char*)bt_hi + swz(tcol[t], tkg[t])) = h;
                *(bf16x8*)((char*)bt_lo + swz(tcol[t], tkg[t])) = l;
            }
            __syncthreads();
            if (ck < 5) loadB(p, ck + 1);
            else if (p < 5) loadB(p + 1, 0);
            #pragma unroll
            for (int ks = 0; ks < 2; ++ks) {
                float av[8];
                const float* xp = xr + ck * 64 + ks * 32 + kq * 8;
                float4 a0 = *(const float4*)xp;
                float4 a1 = *(const float4*)(xp + 4);
                av[0]=a0.x; av[1]=a0.y; av[2]=a0.z; av[3]=a0.w;
                av[4]=a1.x; av[5]=a1.y; av[6]=a1.z; av[7]=a1.w;
                bf16x8 ah, al; split8(av, ah, al);
                #pragma unroll
                for (int f = 0; f < 6; ++f) {
                    int n = wn * 96 + f * 16 + ln;
                    int off = swz(n, ks * 4 + kq);
                    bf16x8 bh = *(const bf16x8*)((char*)bt_hi + off);
                    bf16x8 bl = *(const bf16x8*)((char*)bt_lo + off);
                    acc[f] = __builtin_amdgcn_mfma_f32_16x16x32_bf16(ah, bh, acc[f], 0, 0, 0);
                    acc[f] = __builtin_amdgcn_mfma_f32_16x16x32_bf16(ah, bl, acc[f], 0, 0, 0);
                    acc[f] = __builtin_amdgcn_mfma_f32_16x16x32_bf16(al, bh, acc[f], 0, 0, 0);
                }
            }
        }
        __syncthreads();
        #pragma unroll
        for (int f = 0; f < 6; ++f) {
            int c = wn * 96 + f * 16 + ln;
            int m = c >> 6, d = c & 63, hh = d >> 5, dd = d & 31;
            float bias = qkv_b[m * 384 + p * 64 + d];
            #pragma unroll
            for (int r = 0; r < 4; ++r) {
                int row = wm * 16 + kq * 4 + r;
                if (row < 52) {
                    float val = acc[f][r] + bias;
                    if (m == 0)      qs [(hh * 52 + row) * 36 + dd] = val * SCALE;
                    else if (m == 1) kss[(hh * 52 + row) * 36 + dd] = val;
                    else             vst[(hh * 32 + dd) * 56 + row] = val;
                }
            }
        }
        __syncthreads();
        for (int hh = 0; hh < 2; ++hh) {
            const int h = p * 2 + hh;
            const float* qsh = qs  + hh * 52 * 36;
            const float* ksh = kss + hh * 52 * 36;
            const float* vsh = vst + hh * 32 * 56;
            if (tid < 169) {
                const int n0 = (tid / 13) * 4, m0 = (tid % 13) * 4;
                float s[4][4] = {};
                #pragma unroll
                for (int k = 0; k < 32; k += 4) {
                    float4 qa[4], kb[4];
                    #pragma unroll
                    for (int i = 0; i < 4; ++i) qa[i] = *(const float4*)&qsh[(n0 + i) * 36 + k];
                    #pragma unroll
                    for (int j = 0; j < 4; ++j) kb[j] = *(const float4*)&ksh[(m0 + j) * 36 + k];
                    #pragma unroll
                    for (int i = 0; i < 4; ++i)
                        #pragma unroll
                        for (int j = 0; j < 4; ++j)
                            s[i][j] += qa[i].x * kb[j].x + qa[i].y * kb[j].y +
                                       qa[i].z * kb[j].z + qa[i].w * kb[j].w;
                }
                #pragma unroll
                for (int i = 0; i < 4; ++i)
                    #pragma unroll
                    for (int j = 0; j < 4; ++j)
                        at[(n0 + i) * 56 + m0 + j] = s[i][j];
            }
            __syncthreads();
            for (int r = wv; r < 49; r += 8) {
                float v = (lane < 49) ? at[r * 56 + lane] : -3.4e38f;
                float mx = v;
                #pragma unroll
                for (int off = 32; off; off >>= 1) mx = fmaxf(mx, __shfl_xor(mx, off));
                float ex = (lane < 49) ? __expf(v - mx) : 0.f;
                float ssum = ex;
                #pragma unroll
                for (int off = 32; off; off >>= 1) ssum += __shfl_xor(ssum, off);
                if (lane < 52) {
                    float res = 0.f;
                    if (lane < 49) {
                        int py = r / 7, px = r % 7, qy = lane / 7, qx = lane % 7;
                        int bidx = (py - qy + 6) * 13 + (px - qx + 6);
                        res = ex / ssum + rel_table[bidx * NH + h];
                    }
                    at[r * 56 + lane] = res;
                }
            }
            __syncthreads();
            if (tid < 208) {
                const int n0 = (tid / 16) * 4, d0 = (tid % 16) * 2;
                float o[4][2] = {};
                #pragma unroll
                for (int m2 = 0; m2 < 52; m2 += 4) {
                    float4 pa[4], vb2[2];
                    #pragma unroll
                    for (int i = 0; i < 4; ++i) pa[i] = *(const float4*)&at[(n0 + i) * 56 + m2];
                    #pragma unroll
                    for (int j = 0; j < 2; ++j) vb2[j] = *(const float4*)&vsh[(d0 + j) * 56 + m2];
                    #pragma unroll
                    for (int i = 0; i < 4; ++i)
                        #pragma unroll
                        for (int j = 0; j < 2; ++j)
                            o[i][j] += pa[i].x * vb2[j].x + pa[i].y * vb2[j].y +
                                       pa[i].z * vb2[j].z + pa[i].w * vb2[j].w;
                }
                #pragma unroll
                for (int i = 0; i < 4; ++i) {
                    int n = n0 + i;
                    if (n < 49) {
                        int Yo = wy * 7 + n / 7, Xo = wx * 7 + n % 7;
                        size_t base = (size_t)((bi * 56 + Yo) * 56 + Xo) * 384 + h * 32 + d0;
                        *(float2*)(out + base) = make_float2(o[i][0], o[i][1]);
                    }
                }
            }
            __syncthreads();
        }
    }
}

__global__ __launch_bounds__(512) void wmsa_proj_kernel(
    const float* __restrict__ proj_w, const float* __restrict__ proj_b,
    float* __restrict__ out)
{
    __shared__ __align__(16) char smem[98304];
    u16* bt_hi = (u16*)smem;
    u16* bt_lo = (u16*)(smem + 49152);

    const int tid = threadIdx.x, lane = tid & 63;
    const int wv = tid >> 6, wm = wv >> 1, wn = wv & 1;
    const int ln = lane & 15, kq = lane >> 4;
    const size_t tok0 = (size_t)blockIdx.x * 64;
    const float* xr = out + (tok0 + wm * 16 + ln) * 384;

    int tcol[6], tkg[6];
    #pragma unroll
    for (int t = 0; t < 6; ++t) { int idx = tid + t * 512; tcol[t] = idx % 384; tkg[t] = idx / 384; }
    float rr[6][8];
    auto loadB = [&](int ck) {
        #pragma unroll
        for (int t = 0; t < 6; ++t) {
            const float* wp = proj_w + (size_t)(ck * 64 + tkg[t] * 8) * 384 + tcol[t];
            #pragma unroll
            for (int j = 0; j < 8; ++j) rr[t][j] = wp[(size_t)j * 384];
        }
    };
    loadB(0);

    f32x4 acc[12];
    #pragma unroll
    for (int f = 0; f < 12; ++f) { acc[f][0]=0.f; acc[f][1]=0.f; acc[f][2]=0.f; acc[f][3]=0.f; }

    #pragma unroll 1
    for (int ck = 0; ck < 6; ++ck) {
        __syncthreads();
        #pragma unroll
        for (int t = 0; t < 6; ++t) {
            bf16x8 h, l; split8(rr[t], h, l);
            *(bf16x8*)((char*)bt_hi + swz(tcol[t], tkg[t])) = h;
            *(bf16x8*)((char*)bt_lo + swz(tcol[t], tkg[t])) = l;
        }
        __syncthreads();
        if (ck < 5) loadB(ck + 1);
        #pragma unroll
        for (int ks = 0; ks < 2; ++ks) {
            float av[8];
            const float* xp = xr + ck * 64 + ks * 32 + kq * 8;
            float4 a0 = *(const float4*)xp;
            float4 a1 = *(const float4*)(xp + 4);
            av[0]=a0.x; av[1]=a0.y; av[2]=a0.z; av[3]=a0.w;
            av[4]=a1.x; av[5]=a1.y; av[6]=a1.z; av[7]=a1.w;
            bf16x8 ah, al; split8(av, ah, al);
            #pragma unroll
            for (int f = 0; f < 12; ++f) {
                int n = wn * 192 + f * 16 + ln;
                int off = swz(n, ks * 4 + kq);
                bf16x8 bh = *(const bf16x8*)((char*)bt_hi + off);
                bf16x8 bl = *(const bf16x8*)((char*)bt_lo + off);
                acc[f] = __builtin_amdgcn_mfma_f32_16x16x32_bf16(ah, bh, acc[f], 0, 0, 0);
                acc[f] = __builtin_amdgcn_mfma_f32_16x16x32_bf16(ah, bl, acc[f], 0, 0, 0);
                acc[f] = __builtin_amdgcn_mfma_f32_16x16x32_bf16(al, bh, acc[f], 0, 0, 0);
            }
        }
    }
    __syncthreads();

    #pragma unroll
    for (int f = 0; f < 12; ++f) {
        int n = wn * 192 + f * 16 + ln;
        float pb = proj_b[n];
        #pragma unroll
        for (int r = 0; r < 4; ++r)
            out[(tok0 + wm * 16 + kq * 4 + r) * 384 + n] = acc[f][r] + pb;
    }
}

extern "C" void kernel_launch(void* const* d_in, const int* in_sizes, int n_in,
                              void* d_out, int out_size, void* d_ws, size_t ws_size,
                              hipStream_t stream) {
    const float* x         = (const float*)d_in[0];
    const float* qkv_w     = (const float*)d_in[1];
    const float* qkv_b     = (const float*)d_in[2];
    const float* proj_w    = (const float*)d_in[3];
    const float* proj_b    = (const float*)d_in[4];
    const float* rel_table = (const float*)d_in[5];
    float* out = (float*)d_out;
    char* wsc = (char*)d_ws;

    if (ws_size >= WS_NEED) {
        hipLaunchKernelGGL(prep_kernel, dim3(1536), dim3(384), 0, stream,
                           qkv_w, proj_w, wsc);
        hipLaunchKernelGGL(qkv_gemm_kernel, dim3(2352), dim3(512), 0, stream,
                           x, wsc, qkv_b, wsc);
        hipLaunchKernelGGL(attn_core_kernel, dim3(1024), dim3(256), 0, stream,
                           wsc, rel_table, out);
        hipLaunchKernelGGL(proj_kernel, dim3(784), dim3(512), 0, stream,
                           wsc, proj_b, out);
    } else {
        hipLaunchKernelGGL(wmsa_attn_kernel, dim3(1024), dim3(512), 0, stream,
                           x, qkv_w, qkv_b, rel_table, out);
        hipLaunchKernelGGL(wmsa_proj_kernel, dim3(784), dim3(512), 0, stream,
                           proj_w, proj_b, out);
    }
}